// Round 2
// baseline (67.973 us; speedup 1.0000x reference)
//
#include <hip/hip_runtime.h>

#define KE_CONST 332.0636f
constexpr int TILE = 256;   // max particles per frame handled in tiled path
constexpr int NT   = 1024;  // threads per block (16 waves)
constexpr int NW   = NT / 64;

__global__ __launch_bounds__(NT) void lj_coul_frame_kernel(
    const float* __restrict__ pos, const float* __restrict__ charges,
    const float* __restrict__ lj, const int* __restrict__ frames,
    const int* __restrict__ mols, float* __restrict__ out, int N)
{
    const int f = blockIdx.x;
    const int tid = threadIdx.x;
    const int lane = tid & 63;
    const int wv = tid >> 6;

    __shared__ float jx[TILE], jy[TILE], jz[TILE], jq[TILE], jsig[TILE], jse[TILE];
    __shared__ int   jmol[TILE];
    __shared__ int   sbound[2];   // [0]=lo, [1]=hi
    __shared__ int   spack[NW];
    __shared__ float wsum[NW];

    const int N4 = N >> 2;
    // single-pass path: each thread owns exactly one int4 chunk + its 4 particles
    const bool single = ((N & 3) == 0) && (N4 <= NT);

    int lo, hi;

    if (single) {
        int4  fv = make_int4(0x7fffffff, 0x7fffffff, 0x7fffffff, 0x7fffffff);
        float4 p0 = {0,0,0,0}, p1 = {0,0,0,0}, p2 = {0,0,0,0};
        float4 q4 = {0,0,0,0}, l0 = {0,0,0,0}, l1 = {0,0,0,0};
        int4  m4 = make_int4(0,0,0,0);
        const bool own = tid < N4;
        int nxt = 0x7fffffff;   // sentinel: +inf

        if (own) {
            // ONE round trip: frames chunk + all particle data for this chunk,
            // all loads independent and issued together.
            fv = ((const int4*)frames)[tid];
            p0 = ((const float4*)pos)[tid * 3 + 0];
            p1 = ((const float4*)pos)[tid * 3 + 1];
            p2 = ((const float4*)pos)[tid * 3 + 2];
            q4 = ((const float4*)charges)[tid];
            l0 = ((const float4*)lj)[tid * 2 + 0];
            l1 = ((const float4*)lj)[tid * 2 + 1];
            m4 = ((const int4*)mols)[tid];
            if (tid + 1 < N4) nxt = frames[4 * tid + 4];

            // sorted-boundary detect: exactly one thread writes lo, one writes hi
            const int e0 = fv.x, e1 = fv.y, e2 = fv.z, e3 = fv.w, e4 = nxt;
            if (tid == 0) {
                if (f <= e0) sbound[0] = 0;
                if (f <  e0) sbound[1] = 0;
            }
            if (e0 <  f && f <= e1) sbound[0] = 4 * tid + 1;
            if (e1 <  f && f <= e2) sbound[0] = 4 * tid + 2;
            if (e2 <  f && f <= e3) sbound[0] = 4 * tid + 3;
            if (e3 <  f && f <= e4) sbound[0] = 4 * tid + 4;
            if (e0 <= f && f <  e1) sbound[1] = 4 * tid + 1;
            if (e1 <= f && f <  e2) sbound[1] = 4 * tid + 2;
            if (e2 <= f && f <  e3) sbound[1] = 4 * tid + 3;
            if (e3 <= f && f <  e4) sbound[1] = 4 * tid + 4;
        }
        __syncthreads();
        lo = sbound[0];
        hi = sbound[1];

        // scatter in-register particles into the frame tile (no second global RT)
        if (hi - lo <= TILE && own) {
            const float PX[4] = {p0.x, p0.w, p1.z, p2.y};
            const float PY[4] = {p0.y, p1.x, p1.w, p2.z};
            const float PZ[4] = {p0.z, p1.y, p2.x, p2.w};
            const float QQ[4] = {q4.x, q4.y, q4.z, q4.w};
            const float SG[4] = {l0.x, l0.z, l1.x, l1.z};
            const float EP[4] = {l0.y, l0.w, l1.y, l1.w};
            const int   MO[4] = {m4.x, m4.y, m4.z, m4.w};
            const int   FR[4] = {fv.x, fv.y, fv.z, fv.w};
            #pragma unroll
            for (int p = 0; p < 4; ++p) {
                if (FR[p] == f) {            // equivalent to 4*tid+p in [lo,hi)
                    const int t = 4 * tid + p - lo;
                    jx[t]   = PX[p];
                    jy[t]   = PY[p];
                    jz[t]   = PZ[p];
                    jq[t]   = QQ[p];
                    jsig[t] = SG[p];
                    jse[t]  = sqrtf(EP[p]);  // sqrt(ei*ej) = sqrt(ei)*sqrt(ej)
                    jmol[t] = MO[p];
                }
            }
        }
    } else {
        // --- fallback: packed-count scan (lo in low16, hi in high16) ---
        int pack = 0;
        const int4* f4 = (const int4*)frames;
        for (int k = tid; k < N4; k += NT) {
            const int4 v = f4[k];
            pack += (v.x <  f) + (v.y <  f) + (v.z <  f) + (v.w <  f);
            pack += ((v.x <= f) + (v.y <= f) + (v.z <= f) + (v.w <= f)) << 16;
        }
        for (int k = (N4 << 2) + tid; k < N; k += NT) {
            const int v = frames[k];
            pack += (v < f) + ((v <= f) << 16);
        }
        for (int off = 32; off > 0; off >>= 1)
            pack += __shfl_down(pack, off, 64);
        if (lane == 0) spack[wv] = pack;
        __syncthreads();
        int tot = 0;
        #pragma unroll
        for (int w = 0; w < NW; ++w) tot += spack[w];
        lo = tot & 0xFFFF;
        hi = tot >> 16;

        // stage from global (second round trip — fallback only)
        if (hi - lo <= TILE) {
            for (int t = tid; t < hi - lo; t += NT) {
                const int j = lo + t;
                jx[t]   = pos[3 * j + 0];
                jy[t]   = pos[3 * j + 1];
                jz[t]   = pos[3 * j + 2];
                jq[t]   = charges[j];
                jsig[t] = lj[2 * j + 0];
                jse[t]  = sqrtf(lj[2 * j + 1]);
                jmol[t] = mols[j];
            }
        }
    }

    const int nf = hi - lo;
    float acc = 0.0f;
    __syncthreads();

    if (nf <= TILE) {
        // --- fast path: whole frame in the LDS tile ---
        for (int ti = lane; ti < nf; ti += 64) {
            const float xi  = jx[ti];
            const float yi  = jy[ti];
            const float zi  = jz[ti];
            const float ci  = KE_CONST * jq[ti];
            const float si  = jsig[ti];
            const float sei = jse[ti];
            const int   mi  = jmol[ti];

            for (int t = wv; t < nf; t += NW) {   // wave-uniform t -> LDS broadcast
                const float dx = xi - jx[t];
                const float dy = yi - jy[t];
                const float dz = zi - jz[t];
                const float r2 = dx * dx + dy * dy + dz * dz;
                const float inv_r  = rsqrtf(r2);
                const float inv_r2 = inv_r * inv_r;
                const float coul = ci * jq[t] * inv_r;
                const float s    = si + jsig[t];
                const float sr2  = 0.25f * s * s * inv_r2;
                const float sr6  = sr2 * sr2 * sr2;
                const float ljv  = 4.0f * (sei * jse[t]) * (sr6 * sr6 - sr6);
                acc += (mi != jmol[t]) ? (coul + ljv) : 0.0f;
            }
        }
    } else {
        // --- general path: multi-tile (not expected for these inputs) ---
        for (int jt = lo; jt < hi; jt += TILE) {
            const int cnt = min(TILE, hi - jt);
            for (int t = tid; t < cnt; t += NT) {
                const int j = jt + t;
                jx[t]   = pos[3 * j + 0];
                jy[t]   = pos[3 * j + 1];
                jz[t]   = pos[3 * j + 2];
                jq[t]   = charges[j];
                jsig[t] = lj[2 * j + 0];
                jse[t]  = sqrtf(lj[2 * j + 1]);
                jmol[t] = mols[j];
            }
            __syncthreads();

            for (int i = lo + lane; i < hi; i += 64) {
                const float xi  = pos[3 * i + 0];
                const float yi  = pos[3 * i + 1];
                const float zi  = pos[3 * i + 2];
                const float ci  = KE_CONST * charges[i];
                const float si  = lj[2 * i + 0];
                const float sei = sqrtf(lj[2 * i + 1]);
                const int   mi  = mols[i];

                for (int t = wv; t < cnt; t += NW) {
                    const float dx = xi - jx[t];
                    const float dy = yi - jy[t];
                    const float dz = zi - jz[t];
                    const float r2 = dx * dx + dy * dy + dz * dz;
                    const float inv_r  = rsqrtf(r2);
                    const float inv_r2 = inv_r * inv_r;
                    const float coul = ci * jq[t] * inv_r;
                    const float s    = si + jsig[t];
                    const float sr2  = 0.25f * s * s * inv_r2;
                    const float sr6  = sr2 * sr2 * sr2;
                    const float ljv  = 4.0f * (sei * jse[t]) * (sr6 * sr6 - sr6);
                    acc += (mi != jmol[t]) ? (coul + ljv) : 0.0f;
                }
            }
            __syncthreads();
        }
    }

    // wave (64-lane) shuffle reduction, then cross-wave via LDS
    for (int off = 32; off > 0; off >>= 1)
        acc += __shfl_down(acc, off, 64);
    if (lane == 0) wsum[wv] = acc;
    __syncthreads();
    if (tid == 0) {
        float s = 0.0f;
        #pragma unroll
        for (int w = 0; w < NW; ++w) s += wsum[w];
        out[f] = s;
    }
}

extern "C" void kernel_launch(void* const* d_in, const int* in_sizes, int n_in,
                              void* d_out, int out_size, void* d_ws, size_t ws_size,
                              hipStream_t stream) {
    const float* pos     = (const float*)d_in[0];
    const float* charges = (const float*)d_in[1];
    const float* lj      = (const float*)d_in[2];
    const int*   frames  = (const int*)d_in[3];
    const int*   mols    = (const int*)d_in[4];
    const int    N       = in_sizes[3];   // element count of frames array
    const int    F       = out_size;      // one output per frame

    lj_coul_frame_kernel<<<F, NT, 0, stream>>>(pos, charges, lj, frames, mols,
                                               (float*)d_out, N);
}

// Round 4
// 67.020 us; speedup vs baseline: 1.0142x; 1.0142x over previous
//
#include <hip/hip_runtime.h>

#define KE_CONST 332.0636f
constexpr int WIN = 512;    // speculative window size (= max frame size handled fast)
constexpr int NT  = 1024;   // threads per block (16 waves)
constexpr int NW  = NT / 64;

__global__ __launch_bounds__(NT) void lj_coul_frame_kernel(
    const float* __restrict__ pos, const float* __restrict__ charges,
    const float* __restrict__ lj, const int* __restrict__ frames,
    const int* __restrict__ mols, float* __restrict__ out, int N)
{
    const int f = blockIdx.x;
    const int tid = threadIdx.x;
    const int lane = tid & 63;
    const int wv = tid >> 6;

    __shared__ float jx[WIN], jy[WIN], jz[WIN], jq[WIN], jsig[WIN], jse[WIN];
    __shared__ int   jmol[WIN];
    __shared__ int   sbound[2];   // [0]=lo, [1]=hi (global indices), -1 = not found
    __shared__ int   scov[2];     // coverage flags, unique writers
    __shared__ int   spack[NW];
    __shared__ float wsum[NW];

    // --- speculative window: frames sorted, prefix(f) ~= f*avg +- ~4sigma << margin ---
    const int avg    = N / (int)gridDim.x;
    const int margin = (WIN > avg) ? (WIN - avg) / 2 : 0;
    int wlo = f * avg - margin;
    if (wlo < 0) wlo = 0;
    if (wlo > N - WIN) wlo = (N > WIN) ? (N - WIN) : 0;
    const int whi  = (wlo + WIN < N) ? (wlo + WIN) : N;
    const int wcnt = whi - wlo;
    const bool own = (tid < wcnt);

    // Phase 1: issue ALL global loads (independent -> one memory round trip)
    int   fk = 0, fk1 = 0x7fffffff, mo = 0;
    float px = 0.f, py = 0.f, pz = 0.f, qq = 0.f, sg = 0.f, ep = 0.f;
    if (own) {
        const int g = wlo + tid;
        fk  = frames[g];
        if (g + 1 < N) fk1 = frames[g + 1];
        px  = pos[3 * g + 0];
        py  = pos[3 * g + 1];
        pz  = pos[3 * g + 2];
        qq  = charges[g];
        sg  = lj[2 * g + 0];
        ep  = lj[2 * g + 1];
        mo  = mols[g];
    }
    if (tid < 2) sbound[tid] = -1;   // hardening: init behind its own barrier
    __syncthreads();

    // Phase 2: commit to LDS + boundary/coverage detect (unique writers)
    if (own) {
        const int g = wlo + tid;
        jx[tid]   = px;
        jy[tid]   = py;
        jz[tid]   = pz;
        jq[tid]   = qq;
        jsig[tid] = sg;
        jse[tid]  = sqrtf(ep);   // sqrt(ei*ej) = sqrt(ei)*sqrt(ej)
        jmol[tid] = mo;

        if (tid == 0)        scov[0] = (wlo == 0) ? 1 : (fk < f);
        if (tid == wcnt - 1) scov[1] = (whi == N) ? 1 : (fk > f);

        if (wlo == 0 && tid == 0) {
            if (fk >= f) sbound[0] = 0;
            if (fk >  f) sbound[1] = 0;
        }
        if (fk <  f && fk1 >= f) sbound[0] = g + 1;
        if (fk <= f && fk1 >  f) sbound[1] = g + 1;
    }
    __syncthreads();

    float acc = 0.0f;
    const bool covered = (scov[0] != 0) && (scov[1] != 0) &&
                         (sbound[0] >= 0) && (sbound[1] >= 0);

    if (covered) {
        // --- fast path: frame fully inside the staged window ---
        const int lo   = sbound[0];
        const int hi   = sbound[1];
        int nf   = hi - lo;
        int base = lo - wlo;
        if (nf < 0) nf = 0;
        if (base < 0) base = 0;
        if (base + nf > wcnt) nf = wcnt - base;   // clamp (never hit by proof)

        for (int ti = lane; ti < nf; ti += 64) {
            const float xi  = jx[base + ti];
            const float yi  = jy[base + ti];
            const float zi  = jz[base + ti];
            const float ci  = KE_CONST * jq[base + ti];
            const float si  = jsig[base + ti];
            const float sei = jse[base + ti];
            const int   mi  = jmol[base + ti];

            for (int t = wv; t < nf; t += NW) {   // wave-uniform t -> LDS broadcast
                const float dx = xi - jx[base + t];
                const float dy = yi - jy[base + t];
                const float dz = zi - jz[base + t];
                const float r2 = dx * dx + dy * dy + dz * dz;
                const float inv_r  = rsqrtf(r2);
                const float inv_r2 = inv_r * inv_r;
                const float coul = ci * jq[base + t] * inv_r;
                const float s    = si + jsig[base + t];
                const float sr2  = 0.25f * s * s * inv_r2;
                const float sr6  = sr2 * sr2 * sr2;
                const float ljv  = 4.0f * (sei * jse[base + t]) * (sr6 * sr6 - sr6);
                acc += (mi != jmol[base + t]) ? (coul + ljv) : 0.0f;
            }
        }
    } else {
        // --- fallback (speculation missed): full packed-count scan, then
        //     general multi-tile path. Correct for any frame size/layout. ---
        int pack = 0;
        const int N4 = N >> 2;
        const int4* f4 = (const int4*)frames;
        for (int k = tid; k < N4; k += NT) {
            const int4 v = f4[k];
            pack += (v.x <  f) + (v.y <  f) + (v.z <  f) + (v.w <  f);
            pack += ((v.x <= f) + (v.y <= f) + (v.z <= f) + (v.w <= f)) << 16;
        }
        for (int k = (N4 << 2) + tid; k < N; k += NT) {
            const int v = frames[k];
            pack += (v < f) + ((v <= f) << 16);
        }
        for (int off = 32; off > 0; off >>= 1)
            pack += __shfl_down(pack, off, 64);
        if (lane == 0) spack[wv] = pack;
        __syncthreads();
        int tot = 0;
        #pragma unroll
        for (int w = 0; w < NW; ++w) tot += spack[w];
        const int lo = tot & 0xFFFF;
        const int hi = tot >> 16;

        for (int jt = lo; jt < hi; jt += WIN) {
            const int cnt = min(WIN, hi - jt);
            __syncthreads();   // protect tile reuse across iterations
            for (int t = tid; t < cnt; t += NT) {
                const int j = jt + t;
                jx[t]   = pos[3 * j + 0];
                jy[t]   = pos[3 * j + 1];
                jz[t]   = pos[3 * j + 2];
                jq[t]   = charges[j];
                jsig[t] = lj[2 * j + 0];
                jse[t]  = sqrtf(lj[2 * j + 1]);
                jmol[t] = mols[j];
            }
            __syncthreads();

            for (int i = lo + lane; i < hi; i += 64) {
                const float xi  = pos[3 * i + 0];
                const float yi  = pos[3 * i + 1];
                const float zi  = pos[3 * i + 2];
                const float ci  = KE_CONST * charges[i];
                const float si  = lj[2 * i + 0];
                const float sei = sqrtf(lj[2 * i + 1]);
                const int   mi  = mols[i];

                for (int t = wv; t < cnt; t += NW) {
                    const float dx = xi - jx[t];
                    const float dy = yi - jy[t];
                    const float dz = zi - jz[t];
                    const float r2 = dx * dx + dy * dy + dz * dz;
                    const float inv_r  = rsqrtf(r2);
                    const float inv_r2 = inv_r * inv_r;
                    const float coul = ci * jq[t] * inv_r;
                    const float s    = si + jsig[t];
                    const float sr2  = 0.25f * s * s * inv_r2;
                    const float sr6  = sr2 * sr2 * sr2;
                    const float ljv  = 4.0f * (sei * jse[t]) * (sr6 * sr6 - sr6);
                    acc += (mi != jmol[t]) ? (coul + ljv) : 0.0f;
                }
            }
        }
    }

    // wave (64-lane) shuffle reduction, then cross-wave via LDS
    for (int off = 32; off > 0; off >>= 1)
        acc += __shfl_down(acc, off, 64);
    if (lane == 0) wsum[wv] = acc;
    __syncthreads();
    if (tid == 0) {
        float s = 0.0f;
        #pragma unroll
        for (int w = 0; w < NW; ++w) s += wsum[w];
        out[f] = s;
    }
}

extern "C" void kernel_launch(void* const* d_in, const int* in_sizes, int n_in,
                              void* d_out, int out_size, void* d_ws, size_t ws_size,
                              hipStream_t stream) {
    const float* pos     = (const float*)d_in[0];
    const float* charges = (const float*)d_in[1];
    const float* lj      = (const float*)d_in[2];
    const int*   frames  = (const int*)d_in[3];
    const int*   mols    = (const int*)d_in[4];
    const int    N       = in_sizes[3];   // element count of frames array
    const int    F       = out_size;      // one output per frame

    lj_coul_frame_kernel<<<F, NT, 0, stream>>>(pos, charges, lj, frames, mols,
                                               (float*)d_out, N);
}